// Round 14
// baseline (1163.820 us; speedup 1.0000x reference)
//
#include <hip/hip_runtime.h>
#include <cmath>

#define LEAK 0.2f
#define BN_EPS 1e-5f

static inline int cdiv(long long a, long long b){ return (int)((a + b - 1) / b); }

typedef __attribute__((ext_vector_type(8))) short bf16x8;
typedef __attribute__((ext_vector_type(4))) float f32x4;

// ---- bf16 helpers (manual, RNE) -------------------------------------------
__device__ __forceinline__ float bf2f(unsigned short u){
    return __uint_as_float(((unsigned int)u) << 16);
}
__device__ __forceinline__ unsigned short f2bf(float f){
    unsigned int u = __float_as_uint(f);
    u += 0x7FFFu + ((u >> 16) & 1u);
    return (unsigned short)(u >> 16);
}

// ---------------------------------------------------------------------------
// Wide MFMA bf16 GEMM: 128x256 block tile, BK=32, 4 waves x (4x8) 16x16x32.
// D (bf16) = A[M,K] @ Bt^T. Nc must be a multiple of 256 (grid.x = Nc/256).
// ---------------------------------------------------------------------------
__global__ __launch_bounds__(256) void gemm_mfma_w(
    const unsigned short* __restrict__ A, const unsigned short* __restrict__ Bt,
    unsigned short* __restrict__ D, int M, int K, int lda, int ldb, int ldc)
{
    __shared__ unsigned short As[128 * 40];
    __shared__ unsigned short Bs[256 * 40];
    const int t = threadIdx.x;
    const int row0 = blockIdx.y * 128, col0 = blockIdx.x * 256;
    const int lane = t & 63, wv = t >> 6;
    const int wm = (wv >> 1) << 6;        // 0 / 64
    const int wn = (wv & 1) << 7;         // 0 / 128
    const int lm = lane & 15, lq = lane >> 4;

    f32x4 acc[4][8] = {};

    for (int k0 = 0; k0 < K; k0 += 32) {
        #pragma unroll
        for (int q = t; q < 512; q += 256) {
            int r = q >> 2, c8 = (q & 3) << 3;
            int gr = row0 + r; if (gr >= M) gr = M - 1;
            *(bf16x8*)&As[r * 40 + c8] = *(const bf16x8*)(A + (size_t)gr * lda + k0 + c8);
        }
        #pragma unroll
        for (int q = t; q < 1024; q += 256) {
            int r = q >> 2, c8 = (q & 3) << 3;
            *(bf16x8*)&Bs[r * 40 + c8] = *(const bf16x8*)(Bt + (size_t)(col0 + r) * ldb + k0 + c8);
        }
        __syncthreads();

        bf16x8 af[4], bfr[8];
        #pragma unroll
        for (int mi = 0; mi < 4; ++mi)
            af[mi] = *(const bf16x8*)&As[(wm + mi * 16 + lm) * 40 + lq * 8];
        #pragma unroll
        for (int ni = 0; ni < 8; ++ni)
            bfr[ni] = *(const bf16x8*)&Bs[(wn + ni * 16 + lm) * 40 + lq * 8];
        #pragma unroll
        for (int mi = 0; mi < 4; ++mi)
            #pragma unroll
            for (int ni = 0; ni < 8; ++ni)
                acc[mi][ni] = __builtin_amdgcn_mfma_f32_16x16x32_bf16(
                    af[mi], bfr[ni], acc[mi][ni], 0, 0, 0);
        __syncthreads();
    }

    #pragma unroll
    for (int mi = 0; mi < 4; ++mi) {
        int row_b = row0 + wm + mi * 16 + lq * 4;
        #pragma unroll
        for (int ni = 0; ni < 8; ++ni) {
            int col = col0 + wn + ni * 16 + lm;
            #pragma unroll
            for (int r = 0; r < 4; ++r) {
                int row = row_b + r;
                if (row < M) D[(size_t)row * ldc + col] = f2bf(acc[mi][ni][r]);
            }
        }
    }
}

// ---------------------------------------------------------------------------
// Logits GEMM: C[M, 8] = A[M,K] @ vat^T, vat is 128x K bf16 (rows 8..127 zero).
// ---------------------------------------------------------------------------
__global__ __launch_bounds__(256) void gemm_logits(
    const unsigned short* __restrict__ A, const unsigned short* __restrict__ Bt,
    float* __restrict__ C, int M, int K, int lda)
{
    __shared__ unsigned short As[128 * 40];
    __shared__ unsigned short Bs[128 * 40];
    const int t = threadIdx.x;
    const int row0 = blockIdx.y * 128;
    const int lane = t & 63, wv = t >> 6;
    const int wm = (wv >> 1) << 6, wn = (wv & 1) << 6;
    const int lm = lane & 15, lq = lane >> 4;

    f32x4 acc[4] = {};

    for (int k0 = 0; k0 < K; k0 += 32) {
        #pragma unroll
        for (int q = t; q < 512; q += 256) {
            int r = q >> 2, c8 = (q & 3) << 3;
            int gr = row0 + r; if (gr >= M) gr = M - 1;
            bf16x8 v = *(const bf16x8*)(A + (size_t)gr * lda + k0 + c8);
            *(bf16x8*)&As[r * 40 + c8] = v;
        }
        #pragma unroll
        for (int q = t; q < 512; q += 256) {
            int r = q >> 2, c8 = (q & 3) << 3;
            bf16x8 v = *(const bf16x8*)(Bt + (size_t)r * K + k0 + c8);
            *(bf16x8*)&Bs[r * 40 + c8] = v;
        }
        __syncthreads();

        bf16x8 bfr = *(const bf16x8*)&Bs[(wn + lm) * 40 + lq * 8];
        #pragma unroll
        for (int mi = 0; mi < 4; ++mi) {
            bf16x8 af = *(const bf16x8*)&As[(wm + mi * 16 + lm) * 40 + lq * 8];
            acc[mi] = __builtin_amdgcn_mfma_f32_16x16x32_bf16(af, bfr, acc[mi], 0, 0, 0);
        }
        __syncthreads();
    }

    if (wn == 0 && lm < 8) {
        #pragma unroll
        for (int mi = 0; mi < 4; ++mi) {
            int row_b = row0 + wm + mi * 16 + lq * 4;
            #pragma unroll
            for (int r = 0; r < 4; ++r) {
                int row = row_b + r;
                if (row < M) C[(size_t)row * 8 + lm] = acc[mi][r];
            }
        }
    }
}

// convert fp32 W[K,Nc] -> bf16 W^T[Nc,K]
__global__ void convT(const float* __restrict__ W, unsigned short* __restrict__ Wt, int K, int Nc)
{
    int i = blockIdx.x * blockDim.x + threadIdx.x;
    if (i >= K * Nc) return;
    int k = i / Nc, n = i - k * Nc;
    Wt[(size_t)n * K + k] = f2bf(W[i]);
}

// ---------------------------------------------------------------------------
// Small-M fp32 GEMM, Nc = 128: one output/thread, 2 rows/block, A in LDS.
// ---------------------------------------------------------------------------
template<bool RELU>
__global__ __launch_bounds__(256) void gemm_small(
    const float* __restrict__ A, const float* __restrict__ B,
    const float* __restrict__ bias, float* __restrict__ C,
    int M, int K, int lda, int ldb, int ldc)
{
    __shared__ float As[2][640];
    const int t = threadIdx.x;
    const int r = t >> 7, c = t & 127;
    const int row0 = blockIdx.x * 2;
    for (int i = t; i < 2 * K; i += 256) {
        int rr = i / K, kk = i - rr * K;
        int gr = row0 + rr;
        As[rr][kk] = (gr < M) ? A[(size_t)gr * lda + kk] : 0.f;
    }
    __syncthreads();
    float acc0 = 0.f, acc1 = 0.f;
    for (int k = 0; k < K; k += 8) {
        float4 a0 = *reinterpret_cast<const float4*>(&As[r][k]);
        float4 a1 = *reinterpret_cast<const float4*>(&As[r][k + 4]);
        acc0 += a0.x * B[(size_t)(k + 0) * ldb + c];
        acc1 += a0.y * B[(size_t)(k + 1) * ldb + c];
        acc0 += a0.z * B[(size_t)(k + 2) * ldb + c];
        acc1 += a0.w * B[(size_t)(k + 3) * ldb + c];
        acc0 += a1.x * B[(size_t)(k + 4) * ldb + c];
        acc1 += a1.y * B[(size_t)(k + 5) * ldb + c];
        acc0 += a1.z * B[(size_t)(k + 6) * ldb + c];
        acc1 += a1.w * B[(size_t)(k + 7) * ldb + c];
    }
    int row = row0 + r;
    if (row < M) {
        float v = acc0 + acc1;
        if (bias) v += bias[c];
        if (RELU) v = fmaxf(v, 0.f);
        C[(size_t)row * ldc + c] = v;
    }
}

// ====== vat rows: h -> W@a_src (rows 0..3), W@a_dst (rows 4..7); bf16 =======
__global__ void compute_va_bf(const float* __restrict__ W, const float* __restrict__ a_s,
                              const float* __restrict__ a_d, unsigned short* __restrict__ vat,
                              int K, int HC, int C)
{
    int w = (int)(((long long)blockIdx.x * blockDim.x + threadIdx.x) >> 6);
    int lane = threadIdx.x & 63;
    if (w >= K * 4) return;
    int k = w >> 2, h = w & 3;
    const float* wp = W + (size_t)k * HC + h * C;
    const float* as = a_s + h * C;
    const float* ad = a_d + h * C;
    float s = 0.f, d = 0.f;
    for (int c = lane; c < C; c += 64) {
        float v = wp[c];
        s += v * as[c];
        d += v * ad[c];
    }
    #pragma unroll
    for (int off = 32; off; off >>= 1) {
        s += __shfl_down(s, off);
        d += __shfl_down(d, off);
    }
    if (lane == 0) {
        vat[(size_t)h * K + k] = f2bf(s);
        vat[(size_t)(4 + h) * K + k] = f2bf(d);
    }
}

// ============================ CSR build ====================================
__device__ __forceinline__ int e_src(const int* es, int E, int k){ return k < E ? es[k] : k - E; }
__device__ __forceinline__ int e_dst(const int* ed, int E, int k){ return k < E ? ed[k] : k - E; }

__global__ void fill_i32(int* __restrict__ p, int v, int n)
{
    int i = blockIdx.x * blockDim.x + threadIdx.x;
    if (i < n) p[i] = v;
}

__global__ void hist_dst(const int* __restrict__ ed, int E, int* __restrict__ cnt)
{
    int k = blockIdx.x * blockDim.x + threadIdx.x;
    if (k < E) atomicAdd(&cnt[ed[k]], 1);
}

__global__ __launch_bounds__(256) void scan_blk(const int* __restrict__ cnt,
                                                int* __restrict__ rowptr,
                                                int* __restrict__ bsums, int n)
{
    __shared__ int ts[256];
    const int t = threadIdx.x;
    const int i0 = blockIdx.x * 1024 + t * 4;
    int4 v = {0, 0, 0, 0};
    if (i0 + 3 < n) v = *reinterpret_cast<const int4*>(cnt + i0);
    else {
        if (i0 + 0 < n) v.x = cnt[i0 + 0];
        if (i0 + 1 < n) v.y = cnt[i0 + 1];
        if (i0 + 2 < n) v.z = cnt[i0 + 2];
        if (i0 + 3 < n) v.w = cnt[i0 + 3];
    }
    int lsum = v.x + v.y + v.z + v.w;
    ts[t] = lsum;
    __syncthreads();
    #pragma unroll
    for (int off = 1; off < 256; off <<= 1) {
        int u = (t >= off) ? ts[t - off] : 0;
        __syncthreads();
        ts[t] += u;
        __syncthreads();
    }
    int excl = ts[t] - lsum;
    if (i0 + 0 < n) rowptr[i0 + 0] = excl;
    if (i0 + 1 < n) rowptr[i0 + 1] = excl + v.x;
    if (i0 + 2 < n) rowptr[i0 + 2] = excl + v.x + v.y;
    if (i0 + 3 < n) rowptr[i0 + 3] = excl + v.x + v.y + v.z;
    if (t == 255) bsums[blockIdx.x] = ts[255];
}

__global__ __launch_bounds__(256) void scan_tops(int* __restrict__ bsums,
                                                 int* __restrict__ rowptr, int nb, int n)
{
    __shared__ int ts[256];
    const int t = threadIdx.x;
    int v = (t < nb) ? bsums[t] : 0;
    ts[t] = v;
    __syncthreads();
    #pragma unroll
    for (int off = 1; off < 256; off <<= 1) {
        int u = (t >= off) ? ts[t - off] : 0;
        __syncthreads();
        ts[t] += u;
        __syncthreads();
    }
    if (t < nb) bsums[t] = ts[t] - v;
    if (t == 255) rowptr[n] = ts[255];
}

__global__ void scan_add(int* __restrict__ rowptr, int* __restrict__ cursor,
                         const int* __restrict__ bsums, int n)
{
    int i = blockIdx.x * blockDim.x + threadIdx.x;
    if (i >= n) return;
    int r = rowptr[i] + bsums[i >> 10];
    rowptr[i] = r;
    cursor[i] = r;
}

__global__ void csr_scatter(const int* __restrict__ es, const int* __restrict__ ed,
                            int E, int Etot, int* __restrict__ cursor,
                            int* __restrict__ col, int* __restrict__ dstarr)
{
    int k = blockIdx.x * blockDim.x + threadIdx.x;
    if (k >= Etot) return;
    int sn = e_src(es, E, k), dn = e_dst(ed, E, k);
    int pos = atomicAdd(&cursor[dn], 1);
    col[pos] = sn;
    dstarr[pos] = dn;
}

__global__ void dinv_from_rowptr(const int* __restrict__ rowptr, float* __restrict__ dinv, int n)
{
    int i = blockIdx.x * blockDim.x + threadIdx.x;
    if (i < n) dinv[i] = rsqrtf(fmaxf((float)(rowptr[i + 1] - rowptr[i]), 1.f));
}

__global__ void grp_lb(const int* __restrict__ batch, int N, int G_, int* __restrict__ gptr)
{
    int g = blockIdx.x * blockDim.x + threadIdx.x;
    if (g > G_) return;
    if (g == G_) { gptr[G_] = N; return; }
    int lo = 0, hi = N;
    while (lo < hi) { int mid = (lo + hi) >> 1; if (batch[mid] < g) lo = mid + 1; else hi = mid; }
    gptr[g] = lo;
}

// ====== per-edge softmax weights, all 4 heads (head-major planes) ==========
__global__ void edge_exp4(const int* __restrict__ col, const int* __restrict__ dstarr,
                          int Etot, const float* __restrict__ alsd, float* __restrict__ exq)
{
    int p = blockIdx.x * blockDim.x + threadIdx.x;
    if (p >= Etot) return;
    int sn = col[p], dn = dstarr[p];
    #pragma unroll
    for (int h = 0; h < 4; ++h) {
        float t = alsd[sn * 8 + h] + alsd[dn * 8 + 4 + h];
        t = (t >= 0.f) ? t : LEAK * t;
        exq[(size_t)h * Etot + p] = __expf(t);
    }
}

// ====== layer-1 gather: one wave per node, ALL 4 heads (512 ch) ============
__global__ void gat_gather_all(const int* __restrict__ rowptr, const int* __restrict__ col,
                               const unsigned short* __restrict__ h,
                               const float* __restrict__ exq, int Etot,
                               float* __restrict__ out, int N)
{
    int w = (int)(((long long)blockIdx.x * blockDim.x + threadIdx.x) >> 6);
    int lane = threadIdx.x & 63;
    if (w >= N) return;
    const float* exp_p = exq + (size_t)(lane >> 4) * Etot;
    int r0 = rowptr[w], r1 = rowptr[w + 1];
    float acc[8] = {};
    float ssum = 0.f;
    int e = r0;
    for (; e + 1 < r1; e += 2) {
        int sn0 = col[e], sn1 = col[e + 1];
        float a0 = exp_p[e], a1 = exp_p[e + 1];
        bf16x8 hv0 = *(const bf16x8*)(h + (size_t)sn0 * 512 + lane * 8);
        bf16x8 hv1 = *(const bf16x8*)(h + (size_t)sn1 * 512 + lane * 8);
        ssum += a0 + a1;
        #pragma unroll
        for (int j = 0; j < 8; ++j)
            acc[j] += bf2f((unsigned short)hv0[j]) * a0 + bf2f((unsigned short)hv1[j]) * a1;
    }
    if (e < r1) {
        int sn = col[e];
        float a = exp_p[e];
        bf16x8 hv = *(const bf16x8*)(h + (size_t)sn * 512 + lane * 8);
        ssum += a;
        #pragma unroll
        for (int j = 0; j < 8; ++j) acc[j] += bf2f((unsigned short)hv[j]) * a;
    }
    float inv = 1.f / fmaxf(ssum, 1e-16f);
    float* op = out + (size_t)w * 512 + lane * 8;
    #pragma unroll
    for (int j = 0; j < 8; ++j) op[j] = acc[j] * inv;
}

// ====== layer-2 gather, single head C=256; strided bf16 in, contiguous out =
__global__ void gat_gather256_bf(const int* __restrict__ rowptr, const int* __restrict__ col,
                                 const unsigned short* __restrict__ h, int ldh,
                                 const float* __restrict__ exq,
                                 unsigned short* __restrict__ out, int N)
{
    int w = (int)(((long long)blockIdx.x * blockDim.x + threadIdx.x) >> 6);
    int lane = threadIdx.x & 63;
    if (w >= N) return;
    int r0 = rowptr[w], r1 = rowptr[w + 1];
    float ssum = 0.f;
    float a0 = 0.f, a1 = 0.f, a2 = 0.f, a3 = 0.f;
    int e = r0;
    for (; e + 1 < r1; e += 2) {
        int sn0 = col[e], sn1 = col[e + 1];
        float w0 = exq[e], w1 = exq[e + 1];
        ushort4 hv0 = *reinterpret_cast<const ushort4*>(h + (size_t)sn0 * ldh + lane * 4);
        ushort4 hv1 = *reinterpret_cast<const ushort4*>(h + (size_t)sn1 * ldh + lane * 4);
        ssum += w0 + w1;
        a0 += bf2f(hv0.x) * w0 + bf2f(hv1.x) * w1;
        a1 += bf2f(hv0.y) * w0 + bf2f(hv1.y) * w1;
        a2 += bf2f(hv0.z) * w0 + bf2f(hv1.z) * w1;
        a3 += bf2f(hv0.w) * w0 + bf2f(hv1.w) * w1;
    }
    if (e < r1) {
        int sn = col[e];
        float wv = exq[e];
        ushort4 hv = *reinterpret_cast<const ushort4*>(h + (size_t)sn * ldh + lane * 4);
        ssum += wv;
        a0 += bf2f(hv.x) * wv; a1 += bf2f(hv.y) * wv;
        a2 += bf2f(hv.z) * wv; a3 += bf2f(hv.w) * wv;
    }
    float inv = 1.f / fmaxf(ssum, 1e-16f);
    ushort4 o;
    o.x = f2bf(a0 * inv); o.y = f2bf(a1 * inv);
    o.z = f2bf(a2 * inv); o.w = f2bf(a3 * inv);
    *reinterpret_cast<ushort4*>(out + (size_t)w * 256 + lane * 4) = o;
}

// ====== GCN gather, bf16 input (C=256); wave per node, 2x unroll ============
__global__ void gcn_gather256(const int* __restrict__ rowptr, const int* __restrict__ col,
                              const unsigned short* __restrict__ h,
                              const float* __restrict__ dinv, float* __restrict__ out, int N)
{
    int w = (int)(((long long)blockIdx.x * blockDim.x + threadIdx.x) >> 6);
    int lane = threadIdx.x & 63;
    if (w >= N) return;
    int r0 = rowptr[w], r1 = rowptr[w + 1];
    float a0 = 0.f, a1 = 0.f, a2 = 0.f, a3 = 0.f;
    int e = r0;
    for (; e + 1 < r1; e += 2) {
        int sn0 = col[e], sn1 = col[e + 1];
        float w0 = dinv[sn0], w1 = dinv[sn1];
        ushort4 hv0 = *reinterpret_cast<const ushort4*>(h + (size_t)sn0 * 256 + lane * 4);
        ushort4 hv1 = *reinterpret_cast<const ushort4*>(h + (size_t)sn1 * 256 + lane * 4);
        a0 += bf2f(hv0.x) * w0 + bf2f(hv1.x) * w1;
        a1 += bf2f(hv0.y) * w0 + bf2f(hv1.y) * w1;
        a2 += bf2f(hv0.z) * w0 + bf2f(hv1.z) * w1;
        a3 += bf2f(hv0.w) * w0 + bf2f(hv1.w) * w1;
    }
    if (e < r1) {
        int sn = col[e];
        float wv = dinv[sn];
        ushort4 hv = *reinterpret_cast<const ushort4*>(h + (size_t)sn * 256 + lane * 4);
        a0 += bf2f(hv.x) * wv; a1 += bf2f(hv.y) * wv;
        a2 += bf2f(hv.z) * wv; a3 += bf2f(hv.w) * wv;
    }
    float dn = dinv[w];
    float* op = out + (size_t)w * 256 + lane * 4;
    op[0] = a0 * dn; op[1] = a1 * dn; op[2] = a2 * dn; op[3] = a3 * dn;
}

// ---- BatchNorm: two-stage high-occupancy stats (fp32 input) ---------------
template<int D>
__global__ __launch_bounds__(256) void bn_part(
    const float* __restrict__ x, float* __restrict__ ps, float* __restrict__ pq,
    int M, int Y)
{
    constexpr int DG = D / 4;
    constexpr int P  = 256 / DG;
    const int t = threadIdx.x;
    const int cg = t % DG, ph = t / DG;
    const int y = blockIdx.y;
    const int rows_per = (M + Y - 1) / Y;
    const int r0 = y * rows_per;
    const int r1 = min(r0 + rows_per, M);
    float s0=0,s1=0,s2=0,s3=0,q0=0,q1=0,q2=0,q3=0;
    for (int r = r0 + ph; r < r1; r += P) {
        float4 v = *reinterpret_cast<const float4*>(x + (size_t)r * D + cg * 4);
        s0+=v.x; s1+=v.y; s2+=v.z; s3+=v.w;
        q0+=v.x*v.x; q1+=v.y*v.y; q2+=v.z*v.z; q3+=v.w*v.w;
    }
    __shared__ float ls[P][D];
    __shared__ float lq[P][D];
    ls[ph][cg*4+0]=s0; ls[ph][cg*4+1]=s1; ls[ph][cg*4+2]=s2; ls[ph][cg*4+3]=s3;
    lq[ph][cg*4+0]=q0; lq[ph][cg*4+1]=q1; lq[ph][cg*4+2]=q2; lq[ph][cg*4+3]=q3;
    __syncthreads();
    if (ph == 0) {
        #pragma unroll
        for (int j = 0; j < 4; ++j) {
            float ss = 0.f, qq = 0.f;
            #pragma unroll
            for (int p = 0; p < P; ++p) { ss += ls[p][cg*4+j]; qq += lq[p][cg*4+j]; }
            ps[(size_t)y * D + cg*4 + j] = ss;
            pq[(size_t)y * D + cg*4 + j] = qq;
        }
    }
}

// ---- BN stats, bf16 input with row stride ldx ------------------------------
template<int D>
__global__ __launch_bounds__(256) void bn_part_bf(
    const unsigned short* __restrict__ x, int ldx,
    float* __restrict__ ps, float* __restrict__ pq, int M, int Y)
{
    constexpr int DG = D / 4;
    constexpr int P  = 256 / DG;
    const int t = threadIdx.x;
    const int cg = t % DG, ph = t / DG;
    const int y = blockIdx.y;
    const int rows_per = (M + Y - 1) / Y;
    const int r0 = y * rows_per;
    const int r1 = min(r0 + rows_per, M);
    float s0=0,s1=0,s2=0,s3=0,q0=0,q1=0,q2=0,q3=0;
    for (int r = r0 + ph; r < r1; r += P) {
        ushort4 u = *reinterpret_cast<const ushort4*>(x + (size_t)r * ldx + cg * 4);
        float vx = bf2f(u.x), vy = bf2f(u.y), vz = bf2f(u.z), vw = bf2f(u.w);
        s0+=vx; s1+=vy; s2+=vz; s3+=vw;
        q0+=vx*vx; q1+=vy*vy; q2+=vz*vz; q3+=vw*vw;
    }
    __shared__ float ls[P][D];
    __shared__ float lq[P][D];
    ls[ph][cg*4+0]=s0; ls[ph][cg*4+1]=s1; ls[ph][cg*4+2]=s2; ls[ph][cg*4+3]=s3;
    lq[ph][cg*4+0]=q0; lq[ph][cg*4+1]=q1; lq[ph][cg*4+2]=q2; lq[ph][cg*4+3]=q3;
    __syncthreads();
    if (ph == 0) {
        #pragma unroll
        for (int j = 0; j < 4; ++j) {
            float ss = 0.f, qq = 0.f;
            #pragma unroll
            for (int p = 0; p < P; ++p) { ss += ls[p][cg*4+j]; qq += lq[p][cg*4+j]; }
            ps[(size_t)y * D + cg*4 + j] = ss;
            pq[(size_t)y * D + cg*4 + j] = qq;
        }
    }
}

template<int D>
__global__ __launch_bounds__(256) void bn_reduce_fin(
    const float* __restrict__ ps, const float* __restrict__ pq,
    const float* __restrict__ g, const float* __restrict__ b,
    float* __restrict__ scale, float* __restrict__ shift, int Y, float invM)
{
    constexpr int DG = D / 4;
    constexpr int P  = 256 / DG;
    const int t = threadIdx.x;
    const int cg = t % DG, ph = t / DG;
    float s0=0,s1=0,s2=0,s3=0,q0=0,q1=0,q2=0,q3=0;
    for (int y = ph; y < Y; y += P) {
        float4 a = *reinterpret_cast<const float4*>(ps + (size_t)y * D + cg * 4);
        float4 c = *reinterpret_cast<const float4*>(pq + (size_t)y * D + cg * 4);
        s0+=a.x; s1+=a.y; s2+=a.z; s3+=a.w;
        q0+=c.x; q1+=c.y; q2+=c.z; q3+=c.w;
    }
    __shared__ float ls[P][D];
    __shared__ float lq[P][D];
    ls[ph][cg*4+0]=s0; ls[ph][cg*4+1]=s1; ls[ph][cg*4+2]=s2; ls[ph][cg*4+3]=s3;
    lq[ph][cg*4+0]=q0; lq[ph][cg*4+1]=q1; lq[ph][cg*4+2]=q2; lq[ph][cg*4+3]=q3;
    __syncthreads();
    if (ph == 0) {
        #pragma unroll
        for (int j = 0; j < 4; ++j) {
            int c = cg*4 + j;
            float ss = 0.f, qq = 0.f;
            #pragma unroll
            for (int p = 0; p < P; ++p) { ss += ls[p][c]; qq += lq[p][c]; }
            float mu = ss * invM;
            float var = qq * invM - mu * mu;
            float rs = rsqrtf(var + BN_EPS) * g[c];
            scale[c] = rs;
            shift[c] = b[c] - mu * rs;
        }
    }
}

// relu(bn(x)) fp32 -> bf16 (dst stride ldd)
__global__ void bn_apply_bf164(const float* __restrict__ x, const float* __restrict__ scale,
                               const float* __restrict__ shift, unsigned short* __restrict__ dst,
                               int total4, int Cb4, int ldd)
{
    int i = blockIdx.x * blockDim.x + threadIdx.x;
    if (i >= total4) return;
    int r = i / Cb4, c4 = (i - r * Cb4) * 4;
    float4 v = *reinterpret_cast<const float4*>(x + (size_t)i * 4);
    float4 sc = *reinterpret_cast<const float4*>(scale + c4);
    float4 sh = *reinterpret_cast<const float4*>(shift + c4);
    ushort4 o;
    o.x = f2bf(fmaxf(v.x * sc.x + sh.x, 0.f));
    o.y = f2bf(fmaxf(v.y * sc.y + sh.y, 0.f));
    o.z = f2bf(fmaxf(v.z * sc.z + sh.z, 0.f));
    o.w = f2bf(fmaxf(v.w * sc.w + sh.w, 0.f));
    *reinterpret_cast<ushort4*>(dst + (size_t)r * ldd + c4) = o;
}

// relu(bn(x)) bf16 [M,256] -> bf16 (dst stride ldd, pre-offset column block)
__global__ void bn_apply_b2b(const unsigned short* __restrict__ x,
                             const float* __restrict__ scale, const float* __restrict__ shift,
                             unsigned short* __restrict__ dst, int total4, int ldd)
{
    int i = blockIdx.x * blockDim.x + threadIdx.x;
    if (i >= total4) return;
    int r = i >> 6, c4 = (i & 63) * 4;
    ushort4 u = *reinterpret_cast<const ushort4*>(x + (size_t)r * 256 + c4);
    float4 sc = *reinterpret_cast<const float4*>(scale + c4);
    float4 sh = *reinterpret_cast<const float4*>(shift + c4);
    ushort4 o;
    o.x = f2bf(fmaxf(bf2f(u.x) * sc.x + sh.x, 0.f));
    o.y = f2bf(fmaxf(bf2f(u.y) * sc.y + sh.y, 0.f));
    o.z = f2bf(fmaxf(bf2f(u.z) * sc.z + sh.z, 0.f));
    o.w = f2bf(fmaxf(bf2f(u.w) * sc.w + sh.w, 0.f));
    *reinterpret_cast<ushort4*>(dst + (size_t)r * ldd + c4) = o;
}

__global__ void conv_f2b4(const float* __restrict__ src, unsigned short* __restrict__ dst, int n4)
{
    int i = blockIdx.x * blockDim.x + threadIdx.x;
    if (i >= n4) return;
    float4 v = *reinterpret_cast<const float4*>(src + (size_t)i * 4);
    ushort4 o = { f2bf(v.x), f2bf(v.y), f2bf(v.z), f2bf(v.w) };
    *reinterpret_cast<ushort4*>(dst + (size_t)i * 4) = o;
}

// ---- Pooling with fused BN3 apply+relu ------------------------------------
__global__ __launch_bounds__(256) void pool_gather_bn(const float* __restrict__ h,
                                                      const float* __restrict__ scale,
                                                      const float* __restrict__ shift,
                                                      const int* __restrict__ gptr,
                                                      float* __restrict__ z, int G_)
{
    int g = blockIdx.x;
    int c = threadIdx.x;
    int r0 = gptr[g], r1 = gptr[g + 1];
    float sc = scale[c], sh = shift[c];
    float s = 0.f, m = 0.f;
    for (int i = r0; i < r1; ++i) {
        float v = fmaxf(h[(size_t)i * 256 + c] * sc + sh, 0.f);
        s += v;
        m = fmaxf(m, v);
    }
    float cnt = fmaxf((float)(r1 - r0), 1.f);
    z[(size_t)g * 640 + c] = s / cnt;
    z[(size_t)g * 640 + 256 + c] = m;
}

// ---- final head with fused BNf apply+relu ---------------------------------
__global__ void final_head_bn(const float* __restrict__ f1,
                              const float* __restrict__ scale, const float* __restrict__ shift,
                              const float* __restrict__ Wf2, const float* __restrict__ bf2,
                              float* __restrict__ out, int G_)
{
    int w = (int)(((long long)blockIdx.x * blockDim.x + threadIdx.x) >> 6);
    int lane = threadIdx.x & 63;
    if (w >= G_) return;
    float s = 0.f;
    #pragma unroll
    for (int q = 0; q < 2; ++q) {
        int c = lane + q * 64;
        float v = fmaxf(f1[(size_t)w * 128 + c] * scale[c] + shift[c], 0.f);
        s += v * Wf2[c];
    }
    #pragma unroll
    for (int off = 32; off; off >>= 1) s += __shfl_down(s, off);
    if (lane == 0) out[w] = 1.f / (1.f + __expf(-(s + bf2[0])));
}

__global__ void sentinel(float* __restrict__ out, int n, float v)
{
    int i = blockIdx.x * blockDim.x + threadIdx.x;
    if (i < n) out[i] = v;
}

// ---------------------------------------------------------------------------
extern "C" void kernel_launch(void* const* d_in, const int* in_sizes, int n_in,
                              void* d_out, int out_size, void* d_ws, size_t ws_size,
                              hipStream_t stream)
{
    const float* x    = (const float*)d_in[0];
    const int*   ei   = (const int*)d_in[1];
    const int*   batch= (const int*)d_in[2];
    const float* sfp  = (const float*)d_in[3];
    const float* W1   = (const float*)d_in[4];
    const float* a1s  = (const float*)d_in[5];
    const float* a1d  = (const float*)d_in[6];
    const float* bn1g = (const float*)d_in[8];
    const float* bn1b = (const float*)d_in[9];
    const float* W2   = (const float*)d_in[10];
    const float* a2s  = (const float*)d_in[11];
    const float* a2d  = (const float*)d_in[12];
    const float* bn2g = (const float*)d_in[14];
    const float* bn2b = (const float*)d_in[15];
    const float* Wg   = (const float*)d_in[16];
    const float* bn3g = (const float*)d_in[18];
    const float* bn3b = (const float*)d_in[19];
    const float* Wsm  = (const float*)d_in[20];
    const float* bsm  = (const float*)d_in[21];
    const float* Wf1  = (const float*)d_in[22];
    const float* bnfg = (const float*)d_in[24];
    const float* bnfb = (const float*)d_in[25];
    const float* Wf2  = (const float*)d_in[26];
    const float* bf2  = (const float*)d_in[27];
    float* outp = (float*)d_out;

    const int N    = in_sizes[0] / 64;
    const int E    = in_sizes[1] / 2;
    const int G_   = in_sizes[3] / 128;
    const int Etot = E + N;
    const int* esrc = ei;
    const int* edst = ei + E;
    const int YB = 256;
    const int NB = cdiv(N, 1024);

    // ---- workspace (fp32-element offsets) ----
    // accA+h3acc region (N x 512 fp32) triple-aliased:
    //   layer 1: accL fp32 [N,512] gather output
    //   layer 2: h2all bf16 [N,1024] (pre-BN h2, overwritten in place by post-BN)
    //   GCN:     accA fp32 [N,256] gather output (first half)
    float* ws = (float*)d_ws;
    size_t off = 0;
    float* accA  = ws + off; off += (size_t)N * 256;
    float* h3acc = ws + off; off += (size_t)N * 256;
    float* accL  = accA;
    unsigned short* h2all = (unsigned short*)accA;
    unsigned short* R1 = (unsigned short*)(ws + off); off += (size_t)N * 256; // N*512 bf16
    unsigned short* h1b = R1;
    unsigned short* o1n = R1;
    unsigned short* hb  = (unsigned short*)(ws + off); off += (size_t)N * 128; // N*256 bf16
    unsigned short* xb  = (unsigned short*)(ws + off); off += (size_t)N * 32;  // N*64 bf16
    float* alsd = ws + off; off += (size_t)N * 8;
    float* dinv = ws + off; off += N;
    float* bsc = ws + off; off += 1024;
    float* bsh = ws + off; off += 1024;
    float* ps  = ws + off; off += (size_t)YB * 512;
    float* pq  = ws + off; off += (size_t)YB * 512;
    float* z   = ws + off; off += (size_t)G_ * 640;
    float* f1  = ws + off; off += (size_t)G_ * 128;
    int* rowptr = (int*)(ws + off); off += (size_t)(N + 1);
    int* colc   = (int*)(ws + off); off += (size_t)Etot;
    int* dstarr = (int*)(ws + off); off += (size_t)Etot;
    float* exq  = ws + off; off += (size_t)Etot * 4;
    int* gptr   = (int*)(ws + off); off += (size_t)(G_ + 1);
    int* bsums  = (int*)(ws + off); off += 256;
    unsigned short* vat1 = (unsigned short*)(ws + off); off += 128 * 64 / 2;
    unsigned short* vat2 = (unsigned short*)(ws + off); off += 128 * 512 / 2;
    unsigned short* W1t = (unsigned short*)(ws + off); off += 64 * 512 / 2;
    unsigned short* W2t = (unsigned short*)(ws + off); off += 512 * 1024 / 2;
    unsigned short* Wgt = (unsigned short*)(ws + off); off += 1024 * 256 / 2;
    int* cursor = (int*)alsd;   // alias: cursor dead before alsd is written
    size_t need = off * 4;
    if (ws_size < need) {
        sentinel<<<cdiv(out_size, 256), 256, 0, stream>>>(outp, out_size, (float)(ws_size >> 20));
        return;
    }

    const int BLK = 256;
    dim3 blk(BLK);

    // ============ weight prep (bf16 + transpose), x cast, vat ===============
    convT<<<cdiv(64 * 512, BLK), blk, 0, stream>>>(W1, W1t, 64, 512);
    convT<<<cdiv(512 * 1024, BLK), blk, 0, stream>>>(W2, W2t, 512, 1024);
    convT<<<cdiv(1024 * 256, BLK), blk, 0, stream>>>(Wg, Wgt, 1024, 256);
    conv_f2b4<<<cdiv((long long)N * 16, BLK), blk, 0, stream>>>(x, xb, N * 16);
    fill_i32<<<cdiv(128 * (64 + 512) / 2, BLK), blk, 0, stream>>>((int*)vat1, 0, 128 * (64 + 512) / 2);
    compute_va_bf<<<cdiv(64 * 4 * 64, BLK), blk, 0, stream>>>(W1, a1s, a1d, vat1, 64, 512, 128);
    compute_va_bf<<<cdiv(512 * 4 * 64, BLK), blk, 0, stream>>>(W2, a2s, a2d, vat2, 512, 1024, 256);

    // ================= build CSR (dst -> src) + group bounds ================
    fill_i32<<<cdiv(N, BLK), blk, 0, stream>>>(cursor, 1, N);   // self-loops
    hist_dst<<<cdiv(E, BLK), blk, 0, stream>>>(edst, E, cursor);
    scan_blk<<<NB, blk, 0, stream>>>(cursor, rowptr, bsums, N);
    scan_tops<<<1, blk, 0, stream>>>(bsums, rowptr, NB, N);
    scan_add<<<cdiv(N, BLK), blk, 0, stream>>>(rowptr, cursor, bsums, N);
    csr_scatter<<<cdiv(Etot, BLK), blk, 0, stream>>>(esrc, edst, E, Etot, cursor, colc, dstarr);
    dinv_from_rowptr<<<cdiv(N, BLK), blk, 0, stream>>>(rowptr, dinv, N);
    grp_lb<<<cdiv(G_ + 1, BLK), blk, 0, stream>>>(batch, N, G_, gptr);

    // ================= GAT layer 1 (64 -> 512, all heads batched) ===========
    { dim3 g(2, cdiv(N, 128));
      gemm_mfma_w<<<g, blk, 0, stream>>>(xb, W1t, h1b, N, 64, 64, 64, 512); }
    { dim3 g(1, cdiv(N, 128));
      gemm_logits<<<g, blk, 0, stream>>>(xb, vat1, alsd, N, 64, 64); }
    edge_exp4<<<cdiv(Etot, BLK), blk, 0, stream>>>(colc, dstarr, Etot, alsd, exq);
    gat_gather_all<<<cdiv((long long)N * 64, BLK), blk, 0, stream>>>(
        rowptr, colc, h1b, exq, Etot, accL, N);
    { dim3 g(1, YB); bn_part<512><<<g, blk, 0, stream>>>(accL, ps, pq, N, YB); }
    bn_reduce_fin<512><<<1, blk, 0, stream>>>(ps, pq, bn1g, bn1b, bsc, bsh, YB, 1.f / N);
    bn_apply_bf164<<<cdiv((long long)N * 128, BLK), blk, 0, stream>>>(
        accL, bsc, bsh, o1n, N * 128, 128, 512);

    // ======= layer-2 logits for ALL heads (MFMA) + edge weights ============
    { dim3 g(1, cdiv(N, 128));
      gemm_logits<<<g, blk, 0, stream>>>(o1n, vat2, alsd, N, 512, 512); }
    edge_exp4<<<cdiv(Etot, BLK), blk, 0, stream>>>(colc, dstarr, Etot, alsd, exq);

    // ======= GAT layer 2: ONE batched wide GEMM (512 -> 1024) ==============
    { dim3 g(4, cdiv(N, 128));
      gemm_mfma_w<<<g, blk, 0, stream>>>(o1n, W2t, h2all, N, 512, 512, 512, 1024); }
    // per head: gather -> hb (contiguous), BN stats on hb, apply -> h2all block
    for (int hh = 0; hh < 4; ++hh) {
        gat_gather256_bf<<<cdiv((long long)N * 64, BLK), blk, 0, stream>>>(
            rowptr, colc, h2all + hh * 256, 1024, exq + (size_t)hh * Etot, hb, N);
        { dim3 g(1, YB); bn_part_bf<256><<<g, blk, 0, stream>>>(hb, 256, ps, pq, N, YB); }
        bn_reduce_fin<256><<<1, blk, 0, stream>>>(ps, pq, bn2g + hh * 256, bn2b + hh * 256,
                                                  bsc + hh * 256, bsh + hh * 256, YB, 1.f / N);
        bn_apply_b2b<<<cdiv((long long)N * 64, BLK), blk, 0, stream>>>(
            hb, bsc + hh * 256, bsh + hh * 256, h2all + hh * 256, N * 64, 1024);
    }
    // GCN GEMM: wide MFMA K=1024, Nc=256 -> single column block (A read once)
    { dim3 g(1, cdiv(N, 128));
      gemm_mfma_w<<<g, blk, 0, stream>>>(h2all, Wgt, hb, N, 1024, 1024, 1024, 256); }

    // ================= GCN aggregation (bf16 rows) + BN3 ====================
    gcn_gather256<<<cdiv((long long)N * 64, BLK), blk, 0, stream>>>(
        rowptr, colc, hb, dinv, accA, N);
    { dim3 g(1, YB); bn_part<256><<<g, blk, 0, stream>>>(accA, ps, pq, N, YB); }
    bn_reduce_fin<256><<<1, blk, 0, stream>>>(ps, pq, bn3g, bn3b, bsc, bsh, YB, 1.f / N);

    // ================= Pooling (BN3 + relu fused) ===========================
    pool_gather_bn<<<G_, blk, 0, stream>>>(accA, bsc, bsh, gptr, z, G_);

    // solvent MLP -> z[:, 512:640]
    gemm_small<true><<<cdiv(G_, 2), blk, 0, stream>>>(
        sfp, Wsm, bsm, z + 512, G_, 128, 128, 128, 640);

    // ================= Head (BNf apply folded into final_head) ==============
    gemm_small<false><<<cdiv(G_, 2), blk, 0, stream>>>(
        z, Wf1, nullptr, f1, G_, 640, 640, 128, 128);
    { dim3 g(1, YB); bn_part<128><<<g, blk, 0, stream>>>(f1, ps, pq, G_, YB); }
    bn_reduce_fin<128><<<1, blk, 0, stream>>>(ps, pq, bnfg, bnfb, bsc, bsh, YB, 1.f / G_);
    final_head_bn<<<cdiv((long long)G_ * 64, BLK), blk, 0, stream>>>(
        f1, bsc, bsh, Wf2, bf2, outp, G_);
}

// Round 15
// 998.266 us; speedup vs baseline: 1.1658x; 1.1658x over previous
//
#include <hip/hip_runtime.h>
#include <cmath>

#define LEAK 0.2f
#define BN_EPS 1e-5f

static inline int cdiv(long long a, long long b){ return (int)((a + b - 1) / b); }

typedef __attribute__((ext_vector_type(8))) short bf16x8;
typedef __attribute__((ext_vector_type(4))) float f32x4;

// ---- bf16 helpers (manual, RNE) -------------------------------------------
__device__ __forceinline__ float bf2f(unsigned short u){
    return __uint_as_float(((unsigned int)u) << 16);
}
__device__ __forceinline__ unsigned short f2bf(float f){
    unsigned int u = __float_as_uint(f);
    u += 0x7FFFu + ((u >> 16) & 1u);
    return (unsigned short)(u >> 16);
}

// ---------------------------------------------------------------------------
// MFMA bf16 GEMM (128x128 tile, BK=32, 4 waves x 4x4 16x16x32 MFMAs).
// 1D grid with XCD-aware swizzle: all NX column blocks of one row tile map to
// ids congruent mod 8 -> same XCD (round-robin dispatch) -> A-tile fetched
// into one L2 instead of NX. grid.x = 8 * cdiv(NYT,8) * NX.
// ---------------------------------------------------------------------------
__global__ __launch_bounds__(256) void gemm_mfma(
    const unsigned short* __restrict__ A, const unsigned short* __restrict__ Bt,
    unsigned short* __restrict__ D, int M, int K, int lda, int ldb, int ldc,
    int NX, int NYT)
{
    const int id = blockIdx.x;
    const int xcd = id & 7;
    const int j = id >> 3;
    const int bx = j % NX;
    const int by = (j / NX) * 8 + xcd;
    if (by >= NYT) return;

    __shared__ unsigned short As[128 * 40];
    __shared__ unsigned short Bs[128 * 40];
    const int t = threadIdx.x;
    const int row0 = by * 128, col0 = bx * 128;
    const int lane = t & 63, wv = t >> 6;
    const int wm = (wv >> 1) << 6, wn = (wv & 1) << 6;
    const int lm = lane & 15, lq = lane >> 4;

    f32x4 acc[4][4] = {};

    for (int k0 = 0; k0 < K; k0 += 32) {
        #pragma unroll
        for (int q = t; q < 512; q += 256) {
            int r = q >> 2, c8 = (q & 3) << 3;
            int gr = row0 + r; if (gr >= M) gr = M - 1;
            *(bf16x8*)&As[r * 40 + c8] = *(const bf16x8*)(A + (size_t)gr * lda + k0 + c8);
        }
        #pragma unroll
        for (int q = t; q < 512; q += 256) {
            int r = q >> 2, c8 = (q & 3) << 3;
            *(bf16x8*)&Bs[r * 40 + c8] = *(const bf16x8*)(Bt + (size_t)(col0 + r) * ldb + k0 + c8);
        }
        __syncthreads();

        bf16x8 af[4], bfr[4];
        #pragma unroll
        for (int mi = 0; mi < 4; ++mi)
            af[mi] = *(const bf16x8*)&As[(wm + mi * 16 + lm) * 40 + lq * 8];
        #pragma unroll
        for (int ni = 0; ni < 4; ++ni)
            bfr[ni] = *(const bf16x8*)&Bs[(wn + ni * 16 + lm) * 40 + lq * 8];
        #pragma unroll
        for (int mi = 0; mi < 4; ++mi)
            #pragma unroll
            for (int ni = 0; ni < 4; ++ni)
                acc[mi][ni] = __builtin_amdgcn_mfma_f32_16x16x32_bf16(
                    af[mi], bfr[ni], acc[mi][ni], 0, 0, 0);
        __syncthreads();
    }

    #pragma unroll
    for (int mi = 0; mi < 4; ++mi) {
        int row_b = row0 + wm + mi * 16 + lq * 4;
        #pragma unroll
        for (int ni = 0; ni < 4; ++ni) {
            int col = col0 + wn + ni * 16 + lm;
            #pragma unroll
            for (int r = 0; r < 4; ++r) {
                int row = row_b + r;
                if (row < M) D[(size_t)row * ldc + col] = f2bf(acc[mi][ni][r]);
            }
        }
    }
}

// ---------------------------------------------------------------------------
// Logits GEMM: C[M, 8] = A[M,K] @ vat^T, vat is 128x K bf16 (rows 8..127 zero).
// ---------------------------------------------------------------------------
__global__ __launch_bounds__(256) void gemm_logits(
    const unsigned short* __restrict__ A, const unsigned short* __restrict__ Bt,
    float* __restrict__ C, int M, int K, int lda)
{
    __shared__ unsigned short As[128 * 40];
    __shared__ unsigned short Bs[128 * 40];
    const int t = threadIdx.x;
    const int row0 = blockIdx.y * 128;
    const int lane = t & 63, wv = t >> 6;
    const int wm = (wv >> 1) << 6, wn = (wv & 1) << 6;
    const int lm = lane & 15, lq = lane >> 4;

    f32x4 acc[4] = {};

    for (int k0 = 0; k0 < K; k0 += 32) {
        #pragma unroll
        for (int q = t; q < 512; q += 256) {
            int r = q >> 2, c8 = (q & 3) << 3;
            int gr = row0 + r; if (gr >= M) gr = M - 1;
            bf16x8 v = *(const bf16x8*)(A + (size_t)gr * lda + k0 + c8);
            *(bf16x8*)&As[r * 40 + c8] = v;
        }
        #pragma unroll
        for (int q = t; q < 512; q += 256) {
            int r = q >> 2, c8 = (q & 3) << 3;
            bf16x8 v = *(const bf16x8*)(Bt + (size_t)r * K + k0 + c8);
            *(bf16x8*)&Bs[r * 40 + c8] = v;
        }
        __syncthreads();

        bf16x8 bfr = *(const bf16x8*)&Bs[(wn + lm) * 40 + lq * 8];
        #pragma unroll
        for (int mi = 0; mi < 4; ++mi) {
            bf16x8 af = *(const bf16x8*)&As[(wm + mi * 16 + lm) * 40 + lq * 8];
            acc[mi] = __builtin_amdgcn_mfma_f32_16x16x32_bf16(af, bfr, acc[mi], 0, 0, 0);
        }
        __syncthreads();
    }

    if (wn == 0 && lm < 8) {
        #pragma unroll
        for (int mi = 0; mi < 4; ++mi) {
            int row_b = row0 + wm + mi * 16 + lq * 4;
            #pragma unroll
            for (int r = 0; r < 4; ++r) {
                int row = row_b + r;
                if (row < M) C[(size_t)row * 8 + lm] = acc[mi][r];
            }
        }
    }
}

// convert fp32 W[K,Nc] -> bf16 W^T[Nc,K]
__global__ void convT(const float* __restrict__ W, unsigned short* __restrict__ Wt, int K, int Nc)
{
    int i = blockIdx.x * blockDim.x + threadIdx.x;
    if (i >= K * Nc) return;
    int k = i / Nc, n = i - k * Nc;
    Wt[(size_t)n * K + k] = f2bf(W[i]);
}

// ---------------------------------------------------------------------------
// Small-M fp32 GEMM, Nc = 128: one output/thread, 2 rows/block, A in LDS.
// ---------------------------------------------------------------------------
template<bool RELU>
__global__ __launch_bounds__(256) void gemm_small(
    const float* __restrict__ A, const float* __restrict__ B,
    const float* __restrict__ bias, float* __restrict__ C,
    int M, int K, int lda, int ldb, int ldc)
{
    __shared__ float As[2][640];
    const int t = threadIdx.x;
    const int r = t >> 7, c = t & 127;
    const int row0 = blockIdx.x * 2;
    for (int i = t; i < 2 * K; i += 256) {
        int rr = i / K, kk = i - rr * K;
        int gr = row0 + rr;
        As[rr][kk] = (gr < M) ? A[(size_t)gr * lda + kk] : 0.f;
    }
    __syncthreads();
    float acc0 = 0.f, acc1 = 0.f;
    for (int k = 0; k < K; k += 8) {
        float4 a0 = *reinterpret_cast<const float4*>(&As[r][k]);
        float4 a1 = *reinterpret_cast<const float4*>(&As[r][k + 4]);
        acc0 += a0.x * B[(size_t)(k + 0) * ldb + c];
        acc1 += a0.y * B[(size_t)(k + 1) * ldb + c];
        acc0 += a0.z * B[(size_t)(k + 2) * ldb + c];
        acc1 += a0.w * B[(size_t)(k + 3) * ldb + c];
        acc0 += a1.x * B[(size_t)(k + 4) * ldb + c];
        acc1 += a1.y * B[(size_t)(k + 5) * ldb + c];
        acc0 += a1.z * B[(size_t)(k + 6) * ldb + c];
        acc1 += a1.w * B[(size_t)(k + 7) * ldb + c];
    }
    int row = row0 + r;
    if (row < M) {
        float v = acc0 + acc1;
        if (bias) v += bias[c];
        if (RELU) v = fmaxf(v, 0.f);
        C[(size_t)row * ldc + c] = v;
    }
}

// ====== vat rows: h -> W@a_src (rows 0..3), W@a_dst (rows 4..7); bf16 =======
__global__ void compute_va_bf(const float* __restrict__ W, const float* __restrict__ a_s,
                              const float* __restrict__ a_d, unsigned short* __restrict__ vat,
                              int K, int HC, int C)
{
    int w = (int)(((long long)blockIdx.x * blockDim.x + threadIdx.x) >> 6);
    int lane = threadIdx.x & 63;
    if (w >= K * 4) return;
    int k = w >> 2, h = w & 3;
    const float* wp = W + (size_t)k * HC + h * C;
    const float* as = a_s + h * C;
    const float* ad = a_d + h * C;
    float s = 0.f, d = 0.f;
    for (int c = lane; c < C; c += 64) {
        float v = wp[c];
        s += v * as[c];
        d += v * ad[c];
    }
    #pragma unroll
    for (int off = 32; off; off >>= 1) {
        s += __shfl_down(s, off);
        d += __shfl_down(d, off);
    }
    if (lane == 0) {
        vat[(size_t)h * K + k] = f2bf(s);
        vat[(size_t)(4 + h) * K + k] = f2bf(d);
    }
}

// ============================ CSR build ====================================
__device__ __forceinline__ int e_src(const int* es, int E, int k){ return k < E ? es[k] : k - E; }
__device__ __forceinline__ int e_dst(const int* ed, int E, int k){ return k < E ? ed[k] : k - E; }

__global__ void fill_i32(int* __restrict__ p, int v, int n)
{
    int i = blockIdx.x * blockDim.x + threadIdx.x;
    if (i < n) p[i] = v;
}

__global__ void hist_dst(const int* __restrict__ ed, int E, int* __restrict__ cnt)
{
    int k = blockIdx.x * blockDim.x + threadIdx.x;
    if (k < E) atomicAdd(&cnt[ed[k]], 1);
}

__global__ __launch_bounds__(256) void scan_blk(const int* __restrict__ cnt,
                                                int* __restrict__ rowptr,
                                                int* __restrict__ bsums, int n)
{
    __shared__ int ts[256];
    const int t = threadIdx.x;
    const int i0 = blockIdx.x * 1024 + t * 4;
    int4 v = {0, 0, 0, 0};
    if (i0 + 3 < n) v = *reinterpret_cast<const int4*>(cnt + i0);
    else {
        if (i0 + 0 < n) v.x = cnt[i0 + 0];
        if (i0 + 1 < n) v.y = cnt[i0 + 1];
        if (i0 + 2 < n) v.z = cnt[i0 + 2];
        if (i0 + 3 < n) v.w = cnt[i0 + 3];
    }
    int lsum = v.x + v.y + v.z + v.w;
    ts[t] = lsum;
    __syncthreads();
    #pragma unroll
    for (int off = 1; off < 256; off <<= 1) {
        int u = (t >= off) ? ts[t - off] : 0;
        __syncthreads();
        ts[t] += u;
        __syncthreads();
    }
    int excl = ts[t] - lsum;
    if (i0 + 0 < n) rowptr[i0 + 0] = excl;
    if (i0 + 1 < n) rowptr[i0 + 1] = excl + v.x;
    if (i0 + 2 < n) rowptr[i0 + 2] = excl + v.x + v.y;
    if (i0 + 3 < n) rowptr[i0 + 3] = excl + v.x + v.y + v.z;
    if (t == 255) bsums[blockIdx.x] = ts[255];
}

__global__ __launch_bounds__(256) void scan_tops(int* __restrict__ bsums,
                                                 int* __restrict__ rowptr, int nb, int n)
{
    __shared__ int ts[256];
    const int t = threadIdx.x;
    int v = (t < nb) ? bsums[t] : 0;
    ts[t] = v;
    __syncthreads();
    #pragma unroll
    for (int off = 1; off < 256; off <<= 1) {
        int u = (t >= off) ? ts[t - off] : 0;
        __syncthreads();
        ts[t] += u;
        __syncthreads();
    }
    if (t < nb) bsums[t] = ts[t] - v;
    if (t == 255) rowptr[n] = ts[255];
}

__global__ void scan_add(int* __restrict__ rowptr, int* __restrict__ cursor,
                         const int* __restrict__ bsums, int n)
{
    int i = blockIdx.x * blockDim.x + threadIdx.x;
    if (i >= n) return;
    int r = rowptr[i] + bsums[i >> 10];
    rowptr[i] = r;
    cursor[i] = r;
}

__global__ void csr_scatter(const int* __restrict__ es, const int* __restrict__ ed,
                            int E, int Etot, int* __restrict__ cursor,
                            int* __restrict__ col, int* __restrict__ dstarr)
{
    int k = blockIdx.x * blockDim.x + threadIdx.x;
    if (k >= Etot) return;
    int sn = e_src(es, E, k), dn = e_dst(ed, E, k);
    int pos = atomicAdd(&cursor[dn], 1);
    col[pos] = sn;
    dstarr[pos] = dn;
}

__global__ void dinv_from_rowptr(const int* __restrict__ rowptr, float* __restrict__ dinv, int n)
{
    int i = blockIdx.x * blockDim.x + threadIdx.x;
    if (i < n) dinv[i] = rsqrtf(fmaxf((float)(rowptr[i + 1] - rowptr[i]), 1.f));
}

__global__ void grp_lb(const int* __restrict__ batch, int N, int G_, int* __restrict__ gptr)
{
    int g = blockIdx.x * blockDim.x + threadIdx.x;
    if (g > G_) return;
    if (g == G_) { gptr[G_] = N; return; }
    int lo = 0, hi = N;
    while (lo < hi) { int mid = (lo + hi) >> 1; if (batch[mid] < g) lo = mid + 1; else hi = mid; }
    gptr[g] = lo;
}

// ====== per-edge softmax weights, all 4 heads (head-major planes) ==========
__global__ void edge_exp4(const int* __restrict__ col, const int* __restrict__ dstarr,
                          int Etot, const float* __restrict__ alsd, float* __restrict__ exq)
{
    int p = blockIdx.x * blockDim.x + threadIdx.x;
    if (p >= Etot) return;
    int sn = col[p], dn = dstarr[p];
    #pragma unroll
    for (int h = 0; h < 4; ++h) {
        float t = alsd[sn * 8 + h] + alsd[dn * 8 + 4 + h];
        t = (t >= 0.f) ? t : LEAK * t;
        exq[(size_t)h * Etot + p] = __expf(t);
    }
}

// ====== layer-1 gather: one wave per node, ALL 4 heads (512 ch) ============
__global__ void gat_gather_all(const int* __restrict__ rowptr, const int* __restrict__ col,
                               const unsigned short* __restrict__ h,
                               const float* __restrict__ exq, int Etot,
                               float* __restrict__ out, int N)
{
    int w = (int)(((long long)blockIdx.x * blockDim.x + threadIdx.x) >> 6);
    int lane = threadIdx.x & 63;
    if (w >= N) return;
    const float* exp_p = exq + (size_t)(lane >> 4) * Etot;
    int r0 = rowptr[w], r1 = rowptr[w + 1];
    float acc[8] = {};
    float ssum = 0.f;
    int e = r0;
    for (; e + 1 < r1; e += 2) {
        int sn0 = col[e], sn1 = col[e + 1];
        float a0 = exp_p[e], a1 = exp_p[e + 1];
        bf16x8 hv0 = *(const bf16x8*)(h + (size_t)sn0 * 512 + lane * 8);
        bf16x8 hv1 = *(const bf16x8*)(h + (size_t)sn1 * 512 + lane * 8);
        ssum += a0 + a1;
        #pragma unroll
        for (int j = 0; j < 8; ++j)
            acc[j] += bf2f((unsigned short)hv0[j]) * a0 + bf2f((unsigned short)hv1[j]) * a1;
    }
    if (e < r1) {
        int sn = col[e];
        float a = exp_p[e];
        bf16x8 hv = *(const bf16x8*)(h + (size_t)sn * 512 + lane * 8);
        ssum += a;
        #pragma unroll
        for (int j = 0; j < 8; ++j) acc[j] += bf2f((unsigned short)hv[j]) * a;
    }
    float inv = 1.f / fmaxf(ssum, 1e-16f);
    float* op = out + (size_t)w * 512 + lane * 8;
    #pragma unroll
    for (int j = 0; j < 8; ++j) op[j] = acc[j] * inv;
}

// ====== layer-2 gather, single head C=256; strided bf16 in, contiguous out =
__global__ void gat_gather256_bf(const int* __restrict__ rowptr, const int* __restrict__ col,
                                 const unsigned short* __restrict__ h, int ldh,
                                 const float* __restrict__ exq,
                                 unsigned short* __restrict__ out, int N)
{
    int w = (int)(((long long)blockIdx.x * blockDim.x + threadIdx.x) >> 6);
    int lane = threadIdx.x & 63;
    if (w >= N) return;
    int r0 = rowptr[w], r1 = rowptr[w + 1];
    float ssum = 0.f;
    float a0 = 0.f, a1 = 0.f, a2 = 0.f, a3 = 0.f;
    int e = r0;
    for (; e + 1 < r1; e += 2) {
        int sn0 = col[e], sn1 = col[e + 1];
        float w0 = exq[e], w1 = exq[e + 1];
        ushort4 hv0 = *reinterpret_cast<const ushort4*>(h + (size_t)sn0 * ldh + lane * 4);
        ushort4 hv1 = *reinterpret_cast<const ushort4*>(h + (size_t)sn1 * ldh + lane * 4);
        ssum += w0 + w1;
        a0 += bf2f(hv0.x) * w0 + bf2f(hv1.x) * w1;
        a1 += bf2f(hv0.y) * w0 + bf2f(hv1.y) * w1;
        a2 += bf2f(hv0.z) * w0 + bf2f(hv1.z) * w1;
        a3 += bf2f(hv0.w) * w0 + bf2f(hv1.w) * w1;
    }
    if (e < r1) {
        int sn = col[e];
        float wv = exq[e];
        ushort4 hv = *reinterpret_cast<const ushort4*>(h + (size_t)sn * ldh + lane * 4);
        ssum += wv;
        a0 += bf2f(hv.x) * wv; a1 += bf2f(hv.y) * wv;
        a2 += bf2f(hv.z) * wv; a3 += bf2f(hv.w) * wv;
    }
    float inv = 1.f / fmaxf(ssum, 1e-16f);
    ushort4 o;
    o.x = f2bf(a0 * inv); o.y = f2bf(a1 * inv);
    o.z = f2bf(a2 * inv); o.w = f2bf(a3 * inv);
    *reinterpret_cast<ushort4*>(out + (size_t)w * 256 + lane * 4) = o;
}

// ====== GCN gather, bf16 input (C=256); wave per node, 2x unroll ============
__global__ void gcn_gather256(const int* __restrict__ rowptr, const int* __restrict__ col,
                              const unsigned short* __restrict__ h,
                              const float* __restrict__ dinv, float* __restrict__ out, int N)
{
    int w = (int)(((long long)blockIdx.x * blockDim.x + threadIdx.x) >> 6);
    int lane = threadIdx.x & 63;
    if (w >= N) return;
    int r0 = rowptr[w], r1 = rowptr[w + 1];
    float a0 = 0.f, a1 = 0.f, a2 = 0.f, a3 = 0.f;
    int e = r0;
    for (; e + 1 < r1; e += 2) {
        int sn0 = col[e], sn1 = col[e + 1];
        float w0 = dinv[sn0], w1 = dinv[sn1];
        ushort4 hv0 = *reinterpret_cast<const ushort4*>(h + (size_t)sn0 * 256 + lane * 4);
        ushort4 hv1 = *reinterpret_cast<const ushort4*>(h + (size_t)sn1 * 256 + lane * 4);
        a0 += bf2f(hv0.x) * w0 + bf2f(hv1.x) * w1;
        a1 += bf2f(hv0.y) * w0 + bf2f(hv1.y) * w1;
        a2 += bf2f(hv0.z) * w0 + bf2f(hv1.z) * w1;
        a3 += bf2f(hv0.w) * w0 + bf2f(hv1.w) * w1;
    }
    if (e < r1) {
        int sn = col[e];
        float wv = dinv[sn];
        ushort4 hv = *reinterpret_cast<const ushort4*>(h + (size_t)sn * 256 + lane * 4);
        a0 += bf2f(hv.x) * wv; a1 += bf2f(hv.y) * wv;
        a2 += bf2f(hv.z) * wv; a3 += bf2f(hv.w) * wv;
    }
    float dn = dinv[w];
    float* op = out + (size_t)w * 256 + lane * 4;
    op[0] = a0 * dn; op[1] = a1 * dn; op[2] = a2 * dn; op[3] = a3 * dn;
}

// ---- BatchNorm: two-stage high-occupancy stats (fp32 input) ---------------
template<int D>
__global__ __launch_bounds__(256) void bn_part(
    const float* __restrict__ x, float* __restrict__ ps, float* __restrict__ pq,
    int M, int Y)
{
    constexpr int DG = D / 4;
    constexpr int P  = 256 / DG;
    const int t = threadIdx.x;
    const int cg = t % DG, ph = t / DG;
    const int y = blockIdx.y;
    const int rows_per = (M + Y - 1) / Y;
    const int r0 = y * rows_per;
    const int r1 = min(r0 + rows_per, M);
    float s0=0,s1=0,s2=0,s3=0,q0=0,q1=0,q2=0,q3=0;
    for (int r = r0 + ph; r < r1; r += P) {
        float4 v = *reinterpret_cast<const float4*>(x + (size_t)r * D + cg * 4);
        s0+=v.x; s1+=v.y; s2+=v.z; s3+=v.w;
        q0+=v.x*v.x; q1+=v.y*v.y; q2+=v.z*v.z; q3+=v.w*v.w;
    }
    __shared__ float ls[P][D];
    __shared__ float lq[P][D];
    ls[ph][cg*4+0]=s0; ls[ph][cg*4+1]=s1; ls[ph][cg*4+2]=s2; ls[ph][cg*4+3]=s3;
    lq[ph][cg*4+0]=q0; lq[ph][cg*4+1]=q1; lq[ph][cg*4+2]=q2; lq[ph][cg*4+3]=q3;
    __syncthreads();
    if (ph == 0) {
        #pragma unroll
        for (int j = 0; j < 4; ++j) {
            float ss = 0.f, qq = 0.f;
            #pragma unroll
            for (int p = 0; p < P; ++p) { ss += ls[p][cg*4+j]; qq += lq[p][cg*4+j]; }
            ps[(size_t)y * D + cg*4 + j] = ss;
            pq[(size_t)y * D + cg*4 + j] = qq;
        }
    }
}

// ---- BN stats, bf16 input with row stride ldx ------------------------------
template<int D>
__global__ __launch_bounds__(256) void bn_part_bf(
    const unsigned short* __restrict__ x, int ldx,
    float* __restrict__ ps, float* __restrict__ pq, int M, int Y)
{
    constexpr int DG = D / 4;
    constexpr int P  = 256 / DG;
    const int t = threadIdx.x;
    const int cg = t % DG, ph = t / DG;
    const int y = blockIdx.y;
    const int rows_per = (M + Y - 1) / Y;
    const int r0 = y * rows_per;
    const int r1 = min(r0 + rows_per, M);
    float s0=0,s1=0,s2=0,s3=0,q0=0,q1=0,q2=0,q3=0;
    for (int r = r0 + ph; r < r1; r += P) {
        ushort4 u = *reinterpret_cast<const ushort4*>(x + (size_t)r * ldx + cg * 4);
        float vx = bf2f(u.x), vy = bf2f(u.y), vz = bf2f(u.z), vw = bf2f(u.w);
        s0+=vx; s1+=vy; s2+=vz; s3+=vw;
        q0+=vx*vx; q1+=vy*vy; q2+=vz*vz; q3+=vw*vw;
    }
    __shared__ float ls[P][D];
    __shared__ float lq[P][D];
    ls[ph][cg*4+0]=s0; ls[ph][cg*4+1]=s1; ls[ph][cg*4+2]=s2; ls[ph][cg*4+3]=s3;
    lq[ph][cg*4+0]=q0; lq[ph][cg*4+1]=q1; lq[ph][cg*4+2]=q2; lq[ph][cg*4+3]=q3;
    __syncthreads();
    if (ph == 0) {
        #pragma unroll
        for (int j = 0; j < 4; ++j) {
            float ss = 0.f, qq = 0.f;
            #pragma unroll
            for (int p = 0; p < P; ++p) { ss += ls[p][cg*4+j]; qq += lq[p][cg*4+j]; }
            ps[(size_t)y * D + cg*4 + j] = ss;
            pq[(size_t)y * D + cg*4 + j] = qq;
        }
    }
}

template<int D>
__global__ __launch_bounds__(256) void bn_reduce_fin(
    const float* __restrict__ ps, const float* __restrict__ pq,
    const float* __restrict__ g, const float* __restrict__ b,
    float* __restrict__ scale, float* __restrict__ shift, int Y, float invM)
{
    constexpr int DG = D / 4;
    constexpr int P  = 256 / DG;
    const int t = threadIdx.x;
    const int cg = t % DG, ph = t / DG;
    float s0=0,s1=0,s2=0,s3=0,q0=0,q1=0,q2=0,q3=0;
    for (int y = ph; y < Y; y += P) {
        float4 a = *reinterpret_cast<const float4*>(ps + (size_t)y * D + cg * 4);
        float4 c = *reinterpret_cast<const float4*>(pq + (size_t)y * D + cg * 4);
        s0+=a.x; s1+=a.y; s2+=a.z; s3+=a.w;
        q0+=c.x; q1+=c.y; q2+=c.z; q3+=c.w;
    }
    __shared__ float ls[P][D];
    __shared__ float lq[P][D];
    ls[ph][cg*4+0]=s0; ls[ph][cg*4+1]=s1; ls[ph][cg*4+2]=s2; ls[ph][cg*4+3]=s3;
    lq[ph][cg*4+0]=q0; lq[ph][cg*4+1]=q1; lq[ph][cg*4+2]=q2; lq[ph][cg*4+3]=q3;
    __syncthreads();
    if (ph == 0) {
        #pragma unroll
        for (int j = 0; j < 4; ++j) {
            int c = cg*4 + j;
            float ss = 0.f, qq = 0.f;
            #pragma unroll
            for (int p = 0; p < P; ++p) { ss += ls[p][c]; qq += lq[p][c]; }
            float mu = ss * invM;
            float var = qq * invM - mu * mu;
            float rs = rsqrtf(var + BN_EPS) * g[c];
            scale[c] = rs;
            shift[c] = b[c] - mu * rs;
        }
    }
}

// relu(bn(x)) fp32 -> bf16 (dst stride ldd)
__global__ void bn_apply_bf164(const float* __restrict__ x, const float* __restrict__ scale,
                               const float* __restrict__ shift, unsigned short* __restrict__ dst,
                               int total4, int Cb4, int ldd)
{
    int i = blockIdx.x * blockDim.x + threadIdx.x;
    if (i >= total4) return;
    int r = i / Cb4, c4 = (i - r * Cb4) * 4;
    float4 v = *reinterpret_cast<const float4*>(x + (size_t)i * 4);
    float4 sc = *reinterpret_cast<const float4*>(scale + c4);
    float4 sh = *reinterpret_cast<const float4*>(shift + c4);
    ushort4 o;
    o.x = f2bf(fmaxf(v.x * sc.x + sh.x, 0.f));
    o.y = f2bf(fmaxf(v.y * sc.y + sh.y, 0.f));
    o.z = f2bf(fmaxf(v.z * sc.z + sh.z, 0.f));
    o.w = f2bf(fmaxf(v.w * sc.w + sh.w, 0.f));
    *reinterpret_cast<ushort4*>(dst + (size_t)r * ldd + c4) = o;
}

// relu(bn(x)) bf16 [M,256] -> bf16 (dst stride ldd, pre-offset column block)
__global__ void bn_apply_b2b(const unsigned short* __restrict__ x,
                             const float* __restrict__ scale, const float* __restrict__ shift,
                             unsigned short* __restrict__ dst, int total4, int ldd)
{
    int i = blockIdx.x * blockDim.x + threadIdx.x;
    if (i >= total4) return;
    int r = i >> 6, c4 = (i & 63) * 4;
    ushort4 u = *reinterpret_cast<const ushort4*>(x + (size_t)r * 256 + c4);
    float4 sc = *reinterpret_cast<const float4*>(scale + c4);
    float4 sh = *reinterpret_cast<const float4*>(shift + c4);
    ushort4 o;
    o.x = f2bf(fmaxf(bf2f(u.x) * sc.x + sh.x, 0.f));
    o.y = f2bf(fmaxf(bf2f(u.y) * sc.y + sh.y, 0.f));
    o.z = f2bf(fmaxf(bf2f(u.z) * sc.z + sh.z, 0.f));
    o.w = f2bf(fmaxf(bf2f(u.w) * sc.w + sh.w, 0.f));
    *reinterpret_cast<ushort4*>(dst + (size_t)r * ldd + c4) = o;
}

__global__ void conv_f2b4(const float* __restrict__ src, unsigned short* __restrict__ dst, int n4)
{
    int i = blockIdx.x * blockDim.x + threadIdx.x;
    if (i >= n4) return;
    float4 v = *reinterpret_cast<const float4*>(src + (size_t)i * 4);
    ushort4 o = { f2bf(v.x), f2bf(v.y), f2bf(v.z), f2bf(v.w) };
    *reinterpret_cast<ushort4*>(dst + (size_t)i * 4) = o;
}

// ---- Pooling with fused BN3 apply+relu ------------------------------------
__global__ __launch_bounds__(256) void pool_gather_bn(const float* __restrict__ h,
                                                      const float* __restrict__ scale,
                                                      const float* __restrict__ shift,
                                                      const int* __restrict__ gptr,
                                                      float* __restrict__ z, int G_)
{
    int g = blockIdx.x;
    int c = threadIdx.x;
    int r0 = gptr[g], r1 = gptr[g + 1];
    float sc = scale[c], sh = shift[c];
    float s = 0.f, m = 0.f;
    for (int i = r0; i < r1; ++i) {
        float v = fmaxf(h[(size_t)i * 256 + c] * sc + sh, 0.f);
        s += v;
        m = fmaxf(m, v);
    }
    float cnt = fmaxf((float)(r1 - r0), 1.f);
    z[(size_t)g * 640 + c] = s / cnt;
    z[(size_t)g * 640 + 256 + c] = m;
}

// ---- final head with fused BNf apply+relu ---------------------------------
__global__ void final_head_bn(const float* __restrict__ f1,
                              const float* __restrict__ scale, const float* __restrict__ shift,
                              const float* __restrict__ Wf2, const float* __restrict__ bf2,
                              float* __restrict__ out, int G_)
{
    int w = (int)(((long long)blockIdx.x * blockDim.x + threadIdx.x) >> 6);
    int lane = threadIdx.x & 63;
    if (w >= G_) return;
    float s = 0.f;
    #pragma unroll
    for (int q = 0; q < 2; ++q) {
        int c = lane + q * 64;
        float v = fmaxf(f1[(size_t)w * 128 + c] * scale[c] + shift[c], 0.f);
        s += v * Wf2[c];
    }
    #pragma unroll
    for (int off = 32; off; off >>= 1) s += __shfl_down(s, off);
    if (lane == 0) out[w] = 1.f / (1.f + __expf(-(s + bf2[0])));
}

__global__ void sentinel(float* __restrict__ out, int n, float v)
{
    int i = blockIdx.x * blockDim.x + threadIdx.x;
    if (i < n) out[i] = v;
}

// ---------------------------------------------------------------------------
extern "C" void kernel_launch(void* const* d_in, const int* in_sizes, int n_in,
                              void* d_out, int out_size, void* d_ws, size_t ws_size,
                              hipStream_t stream)
{
    const float* x    = (const float*)d_in[0];
    const int*   ei   = (const int*)d_in[1];
    const int*   batch= (const int*)d_in[2];
    const float* sfp  = (const float*)d_in[3];
    const float* W1   = (const float*)d_in[4];
    const float* a1s  = (const float*)d_in[5];
    const float* a1d  = (const float*)d_in[6];
    const float* bn1g = (const float*)d_in[8];
    const float* bn1b = (const float*)d_in[9];
    const float* W2   = (const float*)d_in[10];
    const float* a2s  = (const float*)d_in[11];
    const float* a2d  = (const float*)d_in[12];
    const float* bn2g = (const float*)d_in[14];
    const float* bn2b = (const float*)d_in[15];
    const float* Wg   = (const float*)d_in[16];
    const float* bn3g = (const float*)d_in[18];
    const float* bn3b = (const float*)d_in[19];
    const float* Wsm  = (const float*)d_in[20];
    const float* bsm  = (const float*)d_in[21];
    const float* Wf1  = (const float*)d_in[22];
    const float* bnfg = (const float*)d_in[24];
    const float* bnfb = (const float*)d_in[25];
    const float* Wf2  = (const float*)d_in[26];
    const float* bf2  = (const float*)d_in[27];
    float* outp = (float*)d_out;

    const int N    = in_sizes[0] / 64;
    const int E    = in_sizes[1] / 2;
    const int G_   = in_sizes[3] / 128;
    const int Etot = E + N;
    const int* esrc = ei;
    const int* edst = ei + E;
    const int YB = 256;
    const int NB = cdiv(N, 1024);
    const int NYT = cdiv(N, 128);                 // GEMM row tiles
    const int NYT8 = cdiv(NYT, 8) * 8;            // padded for swizzle

    // ---- workspace (fp32-element offsets) ----
    float* ws = (float*)d_ws;
    size_t off = 0;
    float* accA  = ws + off; off += (size_t)N * 256;
    float* h3acc = ws + off; off += (size_t)N * 256;
    float* accL  = accA;
    unsigned short* h2all = (unsigned short*)accA;
    unsigned short* R1 = (unsigned short*)(ws + off); off += (size_t)N * 256; // N*512 bf16
    unsigned short* h1b = R1;
    unsigned short* o1n = R1;
    unsigned short* hb  = (unsigned short*)(ws + off); off += (size_t)N * 128; // N*256 bf16
    unsigned short* xb  = (unsigned short*)(ws + off); off += (size_t)N * 32;  // N*64 bf16
    float* alsd = ws + off; off += (size_t)N * 8;
    float* dinv = ws + off; off += N;
    float* bsc = ws + off; off += 1024;
    float* bsh = ws + off; off += 1024;
    float* ps  = ws + off; off += (size_t)YB * 512;
    float* pq  = ws + off; off += (size_t)YB * 512;
    float* z   = ws + off; off += (size_t)G_ * 640;
    float* f1  = ws + off; off += (size_t)G_ * 128;
    int* rowptr = (int*)(ws + off); off += (size_t)(N + 1);
    int* colc   = (int*)(ws + off); off += (size_t)Etot;
    int* dstarr = (int*)(ws + off); off += (size_t)Etot;
    float* exq  = ws + off; off += (size_t)Etot * 4;
    int* gptr   = (int*)(ws + off); off += (size_t)(G_ + 1);
    int* bsums  = (int*)(ws + off); off += 256;
    unsigned short* vat1 = (unsigned short*)(ws + off); off += 128 * 64 / 2;
    unsigned short* vat2 = (unsigned short*)(ws + off); off += 128 * 512 / 2;
    unsigned short* W1t = (unsigned short*)(ws + off); off += 64 * 512 / 2;
    unsigned short* W2t = (unsigned short*)(ws + off); off += 512 * 1024 / 2;
    unsigned short* Wgt = (unsigned short*)(ws + off); off += 1024 * 256 / 2;
    int* cursor = (int*)alsd;   // alias: cursor dead before alsd is written
    size_t need = off * 4;
    if (ws_size < need) {
        sentinel<<<cdiv(out_size, 256), 256, 0, stream>>>(outp, out_size, (float)(ws_size >> 20));
        return;
    }

    const int BLK = 256;
    dim3 blk(BLK);

    // ============ weight prep (bf16 + transpose), x cast, vat ===============
    convT<<<cdiv(64 * 512, BLK), blk, 0, stream>>>(W1, W1t, 64, 512);
    convT<<<cdiv(512 * 1024, BLK), blk, 0, stream>>>(W2, W2t, 512, 1024);
    convT<<<cdiv(1024 * 256, BLK), blk, 0, stream>>>(Wg, Wgt, 1024, 256);
    conv_f2b4<<<cdiv((long long)N * 16, BLK), blk, 0, stream>>>(x, xb, N * 16);
    fill_i32<<<cdiv(128 * (64 + 512) / 2, BLK), blk, 0, stream>>>((int*)vat1, 0, 128 * (64 + 512) / 2);
    compute_va_bf<<<cdiv(64 * 4 * 64, BLK), blk, 0, stream>>>(W1, a1s, a1d, vat1, 64, 512, 128);
    compute_va_bf<<<cdiv(512 * 4 * 64, BLK), blk, 0, stream>>>(W2, a2s, a2d, vat2, 512, 1024, 256);

    // ================= build CSR (dst -> src) + group bounds ================
    fill_i32<<<cdiv(N, BLK), blk, 0, stream>>>(cursor, 1, N);   // self-loops
    hist_dst<<<cdiv(E, BLK), blk, 0, stream>>>(edst, E, cursor);
    scan_blk<<<NB, blk, 0, stream>>>(cursor, rowptr, bsums, N);
    scan_tops<<<1, blk, 0, stream>>>(bsums, rowptr, NB, N);
    scan_add<<<cdiv(N, BLK), blk, 0, stream>>>(rowptr, cursor, bsums, N);
    csr_scatter<<<cdiv(Etot, BLK), blk, 0, stream>>>(esrc, edst, E, Etot, cursor, colc, dstarr);
    dinv_from_rowptr<<<cdiv(N, BLK), blk, 0, stream>>>(rowptr, dinv, N);
    grp_lb<<<cdiv(G_ + 1, BLK), blk, 0, stream>>>(batch, N, G_, gptr);

    // ================= GAT layer 1 (64 -> 512, all heads batched) ===========
    gemm_mfma<<<NYT8 * 4, blk, 0, stream>>>(xb, W1t, h1b, N, 64, 64, 64, 512, 4, NYT);
    { dim3 g(1, NYT);
      gemm_logits<<<g, blk, 0, stream>>>(xb, vat1, alsd, N, 64, 64); }
    edge_exp4<<<cdiv(Etot, BLK), blk, 0, stream>>>(colc, dstarr, Etot, alsd, exq);
    gat_gather_all<<<cdiv((long long)N * 64, BLK), blk, 0, stream>>>(
        rowptr, colc, h1b, exq, Etot, accL, N);
    { dim3 g(1, YB); bn_part<512><<<g, blk, 0, stream>>>(accL, ps, pq, N, YB); }
    bn_reduce_fin<512><<<1, blk, 0, stream>>>(ps, pq, bn1g, bn1b, bsc, bsh, YB, 1.f / N);
    bn_apply_bf164<<<cdiv((long long)N * 128, BLK), blk, 0, stream>>>(
        accL, bsc, bsh, o1n, N * 128, 128, 512);

    // ======= layer-2 logits for ALL heads (MFMA) + edge weights ============
    { dim3 g(1, NYT);
      gemm_logits<<<g, blk, 0, stream>>>(o1n, vat2, alsd, N, 512, 512); }
    edge_exp4<<<cdiv(Etot, BLK), blk, 0, stream>>>(colc, dstarr, Etot, alsd, exq);

    // ======= GAT layer 2: ONE batched GEMM (512 -> 1024), XCD-swizzled =====
    gemm_mfma<<<NYT8 * 8, blk, 0, stream>>>(o1n, W2t, h2all, N, 512, 512, 512, 1024, 8, NYT);
    // per head: gather -> hb (contiguous), BN stats on hb, apply -> h2all block
    for (int hh = 0; hh < 4; ++hh) {
        gat_gather256_bf<<<cdiv((long long)N * 64, BLK), blk, 0, stream>>>(
            rowptr, colc, h2all + hh * 256, 1024, exq + (size_t)hh * Etot, hb, N);
        { dim3 g(1, YB); bn_part_bf<256><<<g, blk, 0, stream>>>(hb, 256, ps, pq, N, YB); }
        bn_reduce_fin<256><<<1, blk, 0, stream>>>(ps, pq, bn2g + hh * 256, bn2b + hh * 256,
                                                  bsc + hh * 256, bsh + hh * 256, YB, 1.f / N);
        bn_apply_b2b<<<cdiv((long long)N * 64, BLK), blk, 0, stream>>>(
            hb, bsc + hh * 256, bsh + hh * 256, h2all + hh * 256, N * 64, 1024);
    }
    // GCN GEMM: K=1024, 2 column blocks, XCD-swizzled (A read ~once)
    gemm_mfma<<<NYT8 * 2, blk, 0, stream>>>(h2all, Wgt, hb, N, 1024, 1024, 1024, 256, 2, NYT);

    // ================= GCN aggregation (bf16 rows) + BN3 ====================
    gcn_gather256<<<cdiv((long long)N * 64, BLK), blk, 0, stream>>>(
        rowptr, colc, hb, dinv, accA, N);
    { dim3 g(1, YB); bn_part<256><<<g, blk, 0, stream>>>(accA, ps, pq, N, YB); }
    bn_reduce_fin<256><<<1, blk, 0, stream>>>(ps, pq, bn3g, bn3b, bsc, bsh, YB, 1.f / N);

    // ================= Pooling (BN3 + relu fused) ===========================
    pool_gather_bn<<<G_, blk, 0, stream>>>(accA, bsc, bsh, gptr, z, G_);

    // solvent MLP -> z[:, 512:640]
    gemm_small<true><<<cdiv(G_, 2), blk, 0, stream>>>(
        sfp, Wsm, bsm, z + 512, G_, 128, 128, 128, 640);

    // ================= Head (BNf apply folded into final_head) ==============
    gemm_small<false><<<cdiv(G_, 2), blk, 0, stream>>>(
        z, Wf1, nullptr, f1, G_, 640, 640, 128, 128);
    { dim3 g(1, YB); bn_part<128><<<g, blk, 0, stream>>>(f1, ps, pq, G_, YB); }
    bn_reduce_fin<128><<<1, blk, 0, stream>>>(ps, pq, bnfg, bnfb, bsc, bsh, YB, 1.f / G_);
    final_head_bn<<<cdiv((long long)G_ * 64, BLK), blk, 0, stream>>>(
        f1, bsc, bsh, Wf2, bf2, outp, G_);
}